// Round 5
// baseline (104.256 us; speedup 1.0000x reference)
//
#include <hip/hip_runtime.h>
#include <hip/hip_bf16.h>
#include <math.h>

#define Bn   8
#define DIM  128
#define Hs   64
#define Ws   64
#define PADn 3
#define GC   16
#define Gn   8
#define CMID 32    // DIM/RED
#define NW   392   // K*K*G
#define NWP  416   // w2b padded rows

typedef __bf16 bf16x8 __attribute__((ext_vector_type(8)));
typedef float  f32x4  __attribute__((ext_vector_type(4)));
typedef _Float16 h2v  __attribute__((ext_vector_type(2)));

__device__ __forceinline__ f32x4 mfma16(bf16x8 a, bf16x8 b, f32x4 c) {
    return __builtin_amdgcn_mfma_f32_16x16x32_bf16(a, b, c, 0, 0, 0);
}

__device__ __forceinline__ __bf16 tobf(float v) {
    __hip_bfloat16 h = __float2bfloat16(v);
    return *reinterpret_cast<__bf16*>(&h);
}

// ---------------- K0: convert weights to bf16 ----------------
__global__ __launch_bounds__(256) void k0_cvt(const float* __restrict__ w1,
        const float* __restrict__ w2,
        const float* __restrict__ pw1, const float* __restrict__ pw2,
        __hip_bfloat16* __restrict__ w1b, __hip_bfloat16* __restrict__ w2b,
        __hip_bfloat16* __restrict__ mw1b, __hip_bfloat16* __restrict__ mw2b) {
    int i = blockIdx.x * 256 + threadIdx.x;   // 32768 threads
    if (i < CMID * DIM) w1b[i] = __float2bfloat16(w1[i]);
    if (i < NWP * CMID)
        w2b[i] = (i < NW * CMID) ? __float2bfloat16(w2[i]) : __float2bfloat16(0.f);
    mw1b[i] = __float2bfloat16(pw1[i]);
    mw2b[i] = __float2bfloat16(pw2[i]);
}

// ---- K2 fused: conv1 MFMA; conv2 MFMA; involution (pk f16); LN; yln bf16 ----
__global__ __launch_bounds__(256) void k2_fused(const float* __restrict__ x,
        const __hip_bfloat16* __restrict__ w1b, const float* __restrict__ b1v,
        const float* __restrict__ bng, const float* __restrict__ bnb,
        const float* __restrict__ bnm, const float* __restrict__ bnv,
        const __hip_bfloat16* __restrict__ w2b, const float* __restrict__ b2v,
        const float* __restrict__ lng, const float* __restrict__ lnb,
        __hip_bfloat16* __restrict__ yln) {
    __shared__ h2v  xp2[2][8][7][72];            // 32.25 KB, double-buffered
    __shared__ h2v  wgt2[49][66];                // 12.9 KB (dup f16 pairs)
    __shared__ __hip_bfloat16 ysb[DIM][66];      // 16.9 KB
    __shared__ __hip_bfloat16 tsh[64][32];       // 4 KB  (t tile)
    __shared__ float ps[4][64], pss[4][64];      // 2 KB
    __shared__ float mu_s[64], rs_s[64];
    int b = blockIdx.x & 7, h = blockIdx.x >> 3;   // XCD-aware: batch b -> XCD b
    int tid = threadIdx.x, lane = tid & 63, wid = tid >> 6;
    int l15 = lane & 15, l4 = lane >> 4;
    int m0 = wid * 16;
    int w = tid & 63, q = tid >> 6;
    size_t pbase = (size_t)b * 4096 + (size_t)h * 64;

    // batched stage of group g's x patch into xp2[buf] (issue all loads first)
    auto stage = [&](int g, int buf) {
#pragma unroll
        for (int half = 0; half < 2; ++half) {
            float v0[8], v1[8];
#pragma unroll
            for (int it = 0; it < 8; ++it) {
                int i = tid + (half * 8 + it) * 256;
                int ccp = i / 490;
                int rem = i - ccp * 490;
                int r = rem / 70, col = rem - r * 70;
                int hh = h + r - PADn, wc = col - PADn;
                bool ok = (i < 3920) & ((unsigned)hh < (unsigned)Hs) &
                          ((unsigned)wc < (unsigned)Ws);
                size_t base = (((size_t)b * DIM + g * GC + ccp) * Hs + hh) * Ws + wc;
                v0[it] = ok ? x[base] : 0.f;
                v1[it] = ok ? x[base + (size_t)8 * Hs * Ws] : 0.f;
            }
#pragma unroll
            for (int it = 0; it < 8; ++it) {
                int i = tid + (half * 8 + it) * 256;
                if (i < 3920) {
                    int ccp = i / 490;
                    int rem = i - ccp * 490;
                    int r = rem / 70, col = rem - r * 70;
                    xp2[buf][ccp][r][col] = (h2v){(_Float16)v0[it], (_Float16)v1[it]};
                }
            }
        }
    };

    // ---- conv1 via MFMA (fused former k1) ----
    bf16x8 afr[4];
#pragma unroll
    for (int ks = 0; ks < 4; ++ks)
#pragma unroll
        for (int i = 0; i < 8; ++i) {
            int c = ks * 32 + l4 * 8 + i;
            afr[ks][i] = tobf(x[(((size_t)b * DIM + c) * Hs + h) * Ws + m0 + l15]);
        }

    stage(0, 0);   // overlap group-0 staging with conv1

    f32x4 acc1[2];
#pragma unroll
    for (int nt = 0; nt < 2; ++nt) acc1[nt] = (f32x4){0.f, 0.f, 0.f, 0.f};
#pragma unroll
    for (int nt = 0; nt < 2; ++nt)
#pragma unroll
        for (int ks = 0; ks < 4; ++ks) {
            bf16x8 bf = *(const bf16x8*)&w1b[(nt * 16 + l15) * DIM + ks * 32 + l4 * 8];
            acc1[nt] = mfma16(afr[ks], bf, acc1[nt]);
        }
#pragma unroll
    for (int nt = 0; nt < 2; ++nt) {
        int o = nt * 16 + l15;
        float sc = bng[o] * rsqrtf(bnv[o] + 1e-5f);
        float sh = bnb[o] - bnm[o] * sc;
        float bv = b1v[o];
#pragma unroll
        for (int r = 0; r < 4; ++r) {
            float v = (acc1[nt][r] + bv) * sc + sh;
            tsh[m0 + l4 * 4 + r][o] = __float2bfloat16(fmaxf(v, 0.f));
        }
    }
    __syncthreads();   // tsh ready; stage(0) writes done

    // conv2 A-frag: pixel m0+l15, channels l4*8..+7
    bf16x8 a_t = *(const bf16x8*)&tsh[m0 + l15][l4 * 8];

    for (int g = 0; g < Gn; ++g) {
        int buf = g & 1;
        // ---- P1: conv2 via MFMA -> wgt2 (dup f16 pairs) ----
        f32x4 acc[4];
#pragma unroll
        for (int nt = 0; nt < 4; ++nt) acc[nt] = (f32x4){0.f, 0.f, 0.f, 0.f};
#pragma unroll
        for (int nt = 0; nt < 4; ++nt) {
            bf16x8 bf = *(const bf16x8*)&w2b[(size_t)(g * 49 + nt * 16 + l15) * CMID + l4 * 8];
            acc[nt] = mfma16(a_t, bf, acc[nt]);
        }
#pragma unroll
        for (int nt = 0; nt < 4; ++nt) {
            int p = nt * 16 + l15;
            if (p < 49) {
                float bias = b2v[g * 49 + p];
#pragma unroll
                for (int r = 0; r < 4; ++r) {
                    _Float16 hf = (_Float16)(acc[nt][r] + bias);
                    wgt2[p][m0 + l4 * 4 + r] = (h2v){hf, hf};
                }
            }
        }
        __syncthreads();   // wgt2 ready; xp2[buf] staging complete

        // ---- P2: prefetch next group's patch + involution ----
        if (g < Gn - 1) stage(g + 1, buf ^ 1);

        h2v wv[49];
#pragma unroll
        for (int p = 0; p < 49; ++p) wv[p] = wgt2[p][w];

#pragma unroll
        for (int pi = 0; pi < 2; ++pi) {
            int ccp = q + pi * 4;
            float acc0 = 0.f, acc1f = 0.f;
#pragma unroll
            for (int r = 0; r < 7; ++r) {
                h2v hacc = (h2v){(_Float16)0.f, (_Float16)0.f};
#pragma unroll
                for (int j = 0; j < 7; ++j)
                    hacc = wv[r * 7 + j] * xp2[buf][ccp][r][w + j] + hacc;
                acc0  += (float)hacc.x;
                acc1f += (float)hacc.y;
            }
            ysb[g * GC + ccp][w]     = __float2bfloat16(acc0);
            ysb[g * GC + ccp + 8][w] = __float2bfloat16(acc1f);
        }
        __syncthreads();   // staging writes done block-wide; wgt2 free
    }

    // ---- LayerNorm ----
    {
        int part = tid >> 6;
        float s = 0.f, ss = 0.f;
#pragma unroll
        for (int c = 0; c < 32; ++c) {
            float v = __bfloat162float(ysb[part * 32 + c][w]);
            s += v; ss = fmaf(v, v, ss);
        }
        ps[part][w] = s; pss[part][w] = ss;
    }
    __syncthreads();
    if (tid < 64) {
        float s = ps[0][tid] + ps[1][tid] + ps[2][tid] + ps[3][tid];
        float ss = pss[0][tid] + pss[1][tid] + pss[2][tid] + pss[3][tid];
        float mu = s * (1.f / DIM);
        float var = ss * (1.f / DIM) - mu * mu;
        mu_s[tid] = mu;
        rs_s[tid] = rsqrtf(var + 1e-6f);
    }
    __syncthreads();
    // unrolled store: 32 independent iterations
#pragma unroll
    for (int it = 0; it < 32; ++it) {
        int i = tid + it * 256;
        int ww = i >> 7, c = i & 127;
        float v = (__bfloat162float(ysb[c][ww]) - mu_s[ww]) * rs_s[ww] * lng[c] + lnb[c];
        yln[(pbase + ww) * DIM + c] = __float2bfloat16(v);
    }
}

// ---------------- K3: MLP via bf16 MFMA + residual ----------------
__global__ __launch_bounds__(256) void k3_mlp_mfma(
        const __hip_bfloat16* __restrict__ yln,   // [P][128] bf16
        const float* __restrict__ x,
        const __hip_bfloat16* __restrict__ w1b,   // [256][128] bf16
        const float* __restrict__ b1v,
        const __hip_bfloat16* __restrict__ w2b,   // [128][256] bf16
        const float* __restrict__ b2v,
        float* __restrict__ out) {
    __shared__ __align__(16) union {
        __hip_bfloat16 y[64][136];
        float          o[64][133];
    } u;
    __shared__ __align__(16) __hip_bfloat16 zsh[4][16][264];

    int b = blockIdx.x & 7, h = blockIdx.x >> 3;   // XCD-aware
    int tid = threadIdx.x;
    int lane = tid & 63, wid = tid >> 6;
    int l15 = lane & 15, l4 = lane >> 4;
    size_t pbase = ((size_t)b * Hs + h) * Ws;

#pragma unroll
    for (int it = 0; it < 4; ++it) {
        int i = tid + it * 256;
        int row = i >> 4, ch = i & 15;
        *(ulonglong2*)&u.y[row][ch * 8] =
            *(const ulonglong2*)&yln[(pbase + row) * DIM + ch * 8];
    }
    __syncthreads();

    int m0 = wid * 16;

    f32x4 acc[16];
#pragma unroll
    for (int n = 0; n < 16; ++n) acc[n] = (f32x4){0.f, 0.f, 0.f, 0.f};
#pragma unroll
    for (int ks = 0; ks < 4; ++ks) {
        bf16x8 a = *(const bf16x8*)&u.y[m0 + l15][ks * 32 + l4 * 8];
#pragma unroll
        for (int n = 0; n < 16; ++n) {
            bf16x8 bf = *(const bf16x8*)&w1b[(n * 16 + l15) * DIM + ks * 32 + l4 * 8];
            acc[n] = mfma16(a, bf, acc[n]);
        }
    }
    __syncthreads();

#pragma unroll
    for (int n = 0; n < 16; ++n) {
        float bv = b1v[n * 16 + l15];
#pragma unroll
        for (int r = 0; r < 4; ++r) {
            float v = acc[n][r] + bv;
            v = v * 0.5f * (1.f + erff(v * 0.70710678118f));
            zsh[wid][l4 * 4 + r][n * 16 + l15] = __float2bfloat16(v);
        }
    }

    f32x4 acc2[8];
#pragma unroll
    for (int n = 0; n < 8; ++n) acc2[n] = (f32x4){0.f, 0.f, 0.f, 0.f};
#pragma unroll
    for (int ks = 0; ks < 8; ++ks) {
        bf16x8 a = *(const bf16x8*)&zsh[wid][l15][ks * 32 + l4 * 8];
#pragma unroll
        for (int n = 0; n < 8; ++n) {
            bf16x8 bf = *(const bf16x8*)&w2b[(n * 16 + l15) * 256 + ks * 32 + l4 * 8];
            acc2[n] = mfma16(a, bf, acc2[n]);
        }
    }

#pragma unroll
    for (int n = 0; n < 8; ++n) {
        float bv = b2v[n * 16 + l15];
#pragma unroll
        for (int r = 0; r < 4; ++r)
            u.o[m0 + l4 * 4 + r][n * 16 + l15] = acc2[n][r] + bv;
    }
    __syncthreads();

    // residual + store: issue all 32 x-loads first, then combine
    float xr[32];
#pragma unroll
    for (int it = 0; it < 32; ++it) {
        int i = tid + it * 256;
        int c = i >> 6, ww = i & 63;
        xr[it] = x[(((size_t)b * DIM + c) * Hs + h) * Ws + ww];
    }
#pragma unroll
    for (int it = 0; it < 32; ++it) {
        int i = tid + it * 256;
        int c = i >> 6, ww = i & 63;
        out[(((size_t)b * DIM + c) * Hs + h) * Ws + ww] = u.o[ww][c] + xr[it];
    }
}

extern "C" void kernel_launch(void* const* d_in, const int* in_sizes, int n_in,
                              void* d_out, int out_size, void* d_ws, size_t ws_size,
                              hipStream_t stream) {
    const float* x       = (const float*)d_in[0];
    const float* conv1_w = (const float*)d_in[1];
    const float* conv1_b = (const float*)d_in[2];
    const float* bn_g    = (const float*)d_in[3];
    const float* bn_b    = (const float*)d_in[4];
    const float* bn_mean = (const float*)d_in[5];
    const float* bn_var  = (const float*)d_in[6];
    const float* conv2_w = (const float*)d_in[7];
    const float* conv2_b = (const float*)d_in[8];
    const float* ln_g    = (const float*)d_in[9];
    const float* ln_b    = (const float*)d_in[10];
    const float* pw1_w   = (const float*)d_in[11];
    const float* pw1_b   = (const float*)d_in[12];
    const float* pw2_w   = (const float*)d_in[13];
    const float* pw2_b   = (const float*)d_in[14];
    float* out = (float*)d_out;

    char* ws = (char*)d_ws;
    __hip_bfloat16* y_ln = (__hip_bfloat16*)ws;                      // 8 MB
    __hip_bfloat16* w1b  = (__hip_bfloat16*)(ws + 8388608);          // 8 KB
    __hip_bfloat16* w2b  = (__hip_bfloat16*)(ws + 8396800);          // 26 KB
    __hip_bfloat16* mw1b = (__hip_bfloat16*)(ws + 8423424);          // 64 KB
    __hip_bfloat16* mw2b = (__hip_bfloat16*)(ws + 8488960);          // 64 KB

    dim3 block(256);
    hipLaunchKernelGGL(k0_cvt, dim3(128), block, 0, stream,
                       conv1_w, conv2_w, pw1_w, pw2_w, w1b, w2b, mw1b, mw2b);
    hipLaunchKernelGGL(k2_fused, dim3(Bn * Hs), block, 0, stream,
                       x, w1b, conv1_b, bn_g, bn_b, bn_mean, bn_var,
                       w2b, conv2_b, ln_g, ln_b, y_ln);
    hipLaunchKernelGGL(k3_mlp_mfma, dim3(Bn * Hs), block, 0, stream,
                       y_ln, x, mw1b, pw1_b, mw2b, pw2_b, out);
}